// Round 1
// baseline (424.726 us; speedup 1.0000x reference)
//
#include <hip/hip_runtime.h>
#include <hip/hip_bf16.h>

typedef __attribute__((ext_vector_type(8))) short bf16x8;
typedef __attribute__((ext_vector_type(4))) float f32x4;

#define SEQ 2048
#define DMODEL 1024
#define NH 16
#define HD 64
#define BATCH 4
#define BHTOT 64          // BATCH*NH
#define BS 8192           // BATCH*SEQ
#define QKV_ELEMS 8388608 // BS*DMODEL

__device__ __forceinline__ ushort f2bf(float f) {
  union { float f; unsigned u; } v; v.f = f;
  unsigned r = (v.u + 0x7FFFu + ((v.u >> 16) & 1u)) >> 16;
  return (ushort)r;
}

// ---------------- weight f32 -> bf16 convert ----------------
__global__ __launch_bounds__(256) void convert_w(
    const float* __restrict__ w0, const float* __restrict__ w1,
    const float* __restrict__ w2, ushort* __restrict__ out) {
  const float* src = blockIdx.y == 0 ? w0 : (blockIdx.y == 1 ? w1 : w2);
  size_t e = ((size_t)blockIdx.x * 256 + threadIdx.x) * 4;
  float4 v = *(const float4*)(src + e);
  ushort4 o = { f2bf(v.x), f2bf(v.y), f2bf(v.z), f2bf(v.w) };
  *(ushort4*)(out + (size_t)blockIdx.y * 1048576 + e) = o;
}

// ---------------- QKV projection GEMM ----------------
// out[m][n] = sum_k X[m][k] * W[n][k] + bias[n], stored bf16 in [B,H,S,HD]
__global__ __launch_bounds__(256) void qkv_gemm(
    const float* __restrict__ x0, const float* __restrict__ x1, const float* __restrict__ x2,
    const ushort* __restrict__ Wb,
    const float* __restrict__ bq, const float* __restrict__ bk, const float* __restrict__ bv,
    ushort* __restrict__ qkv) {
  __shared__ ushort sA[128][40];  // +8 pad: row stride 80B (5x16B) -> 2-way bank alias (free)
  __shared__ ushort sB[128][40];

  const int z = blockIdx.z;
  const float* X = z == 0 ? x0 : (z == 1 ? x1 : x2);
  const ushort* W = Wb + (size_t)z * 1048576;
  const float* bias = z == 0 ? bq : (z == 1 ? bk : bv);
  ushort* out = qkv + (size_t)z * QKV_ELEMS;

  const int t = threadIdx.x;
  const int m0 = blockIdx.x * 128;
  const int n0 = blockIdx.y * 128;
  const int w = t >> 6, l = t & 63, lr = l & 15, lhi = l >> 4;
  const int wr = (w >> 1) * 64, wc = (w & 1) * 64;

  f32x4 acc[4][4];
#pragma unroll
  for (int i = 0; i < 4; i++)
#pragma unroll
    for (int j = 0; j < 4; j++) acc[i][j] = (f32x4){0.f, 0.f, 0.f, 0.f};

  for (int k0 = 0; k0 < DMODEL; k0 += 32) {
#pragma unroll
    for (int i = 0; i < 4; i++) {
      int e = i * 256 + t;
      int row = e >> 3, col = (e & 7) * 4;
      float4 a = *(const float4*)(X + (size_t)(m0 + row) * DMODEL + k0 + col);
      ushort4 ab = { f2bf(a.x), f2bf(a.y), f2bf(a.z), f2bf(a.w) };
      *(ushort4*)(&sA[row][col]) = ab;
      ushort4 bb = *(const ushort4*)(W + (size_t)(n0 + row) * DMODEL + k0 + col);
      *(ushort4*)(&sB[row][col]) = bb;
    }
    __syncthreads();
    bf16x8 af[4], bfr[4];
#pragma unroll
    for (int mi = 0; mi < 4; mi++) af[mi] = *(const bf16x8*)(&sA[wr + mi * 16 + lr][lhi * 8]);
#pragma unroll
    for (int ni = 0; ni < 4; ni++) bfr[ni] = *(const bf16x8*)(&sB[wc + ni * 16 + lr][lhi * 8]);
#pragma unroll
    for (int mi = 0; mi < 4; mi++)
#pragma unroll
      for (int ni = 0; ni < 4; ni++)
        acc[mi][ni] = __builtin_amdgcn_mfma_f32_16x16x32_bf16(af[mi], bfr[ni], acc[mi][ni], 0, 0, 0);
    __syncthreads();
  }

  // epilogue: C layout col=lane&15, row=(lane>>4)*4+reg
#pragma unroll
  for (int mi = 0; mi < 4; mi++) {
#pragma unroll
    for (int ni = 0; ni < 4; ni++) {
      int col = n0 + wc + ni * 16 + lr;
      float bsv = bias[col];
      int h = col >> 6, hd = col & 63;
#pragma unroll
      for (int r = 0; r < 4; r++) {
        int row = m0 + wr + mi * 16 + lhi * 4 + r;
        int b = row >> 11, s = row & 2047;
        float vv = acc[mi][ni][r] + bsv;
        out[(((size_t)(b * NH + h)) * SEQ + s) * HD + hd] = f2bf(vv);
      }
    }
  }
}

// ---------------- flash attention ----------------
// qkv: bf16 [3][BH][SEQ][HD]; out: f32 [B,S,D]
__global__ __launch_bounds__(256) void attn_kernel(const ushort* __restrict__ qkv,
                                                   float* __restrict__ out) {
  __shared__ ushort Vt[64][72];      // V^T tile: [hd][kv], stride 144B
  __shared__ ushort Pl[4][16][72];   // per-wave P tile: [qrow][kv], stride 144B

  const int bid = blockIdx.x;
  const int bh = bid >> 5, qt = bid & 31;
  const int q0 = qt * 64;
  const int t = threadIdx.x, w = t >> 6, l = t & 63, lr = l & 15, lhi = l >> 4;

  const ushort* q = qkv;
  const ushort* k = qkv + QKV_ELEMS;
  const ushort* v = qkv + 2 * (size_t)QKV_ELEMS;
  const size_t base = (size_t)bh * SEQ * HD;

  // hoist Q fragments (A-frag: row=l&15, k=(l>>4)*8..+8)
  bf16x8 aq[2];
  {
    int qrow = q0 + w * 16 + lr;
#pragma unroll
    for (int kk = 0; kk < 2; kk++)
      aq[kk] = *(const bf16x8*)(q + base + (size_t)qrow * HD + kk * 32 + lhi * 8);
  }

  float m[4], lsum[4];
  f32x4 acc_o[4];
#pragma unroll
  for (int r = 0; r < 4; r++) { m[r] = -1e30f; lsum[r] = 0.f; }
#pragma unroll
  for (int i = 0; i < 4; i++) acc_o[i] = (f32x4){0.f, 0.f, 0.f, 0.f};

  for (int kv0 = 0; kv0 < SEQ; kv0 += 64) {
    // stage V^T (all 256 threads): V[kv][hd] -> Vt[hd][kv]
#pragma unroll
    for (int i = 0; i < 8; i++) {
      int e2 = (i * 256 + t) * 2;
      int kv = e2 >> 6, hd = e2 & 63;
      unsigned vv = *(const unsigned*)(v + base + (size_t)(kv0 + kv) * HD + hd);
      Vt[hd][kv] = (ushort)(vv & 0xffffu);
      Vt[hd + 1][kv] = (ushort)(vv >> 16);
    }

    // QK^T: scores[16 q][64 kv] per wave, K read straight from global (L2-resident)
    f32x4 sc[4];
#pragma unroll
    for (int nb = 0; nb < 4; nb++) sc[nb] = (f32x4){0.f, 0.f, 0.f, 0.f};
#pragma unroll
    for (int nb = 0; nb < 4; nb++) {
#pragma unroll
      for (int kk = 0; kk < 2; kk++) {
        bf16x8 bk = *(const bf16x8*)(k + base + (size_t)(kv0 + nb * 16 + lr) * HD + kk * 32 + lhi * 8);
        sc[nb] = __builtin_amdgcn_mfma_f32_16x16x32_bf16(aq[kk], bk, sc[nb], 0, 0, 0);
      }
    }
    __syncthreads();  // Vt writes visible

    // online softmax (rows replicated across the 16 lanes sharing lhi)
    float p[4][4];
#pragma unroll
    for (int r = 0; r < 4; r++) {
      float tm = fmaxf(fmaxf(sc[0][r], sc[1][r]), fmaxf(sc[2][r], sc[3][r])) * 0.125f;
#pragma unroll
      for (int off = 1; off < 16; off <<= 1) tm = fmaxf(tm, __shfl_xor(tm, off));
      float mn = fmaxf(m[r], tm);
      float alpha = __expf(m[r] - mn);
      float rs = 0.f;
#pragma unroll
      for (int nb = 0; nb < 4; nb++) {
        float pp = __expf(sc[nb][r] * 0.125f - mn);
        p[nb][r] = pp;
        rs += pp;
      }
#pragma unroll
      for (int off = 1; off < 16; off <<= 1) rs += __shfl_xor(rs, off);
      lsum[r] = lsum[r] * alpha + rs;
      m[r] = mn;
#pragma unroll
      for (int nbh = 0; nbh < 4; nbh++) acc_o[nbh][r] *= alpha;
    }

    // P (bf16) -> per-wave LDS, then PV MFMA
#pragma unroll
    for (int nb = 0; nb < 4; nb++)
#pragma unroll
      for (int r = 0; r < 4; r++)
        Pl[w][lhi * 4 + r][nb * 16 + lr] = f2bf(p[nb][r]);

    bf16x8 ap[2];
#pragma unroll
    for (int kk = 0; kk < 2; kk++) ap[kk] = *(const bf16x8*)(&Pl[w][lr][kk * 32 + lhi * 8]);
#pragma unroll
    for (int nbh = 0; nbh < 4; nbh++) {
#pragma unroll
      for (int kk = 0; kk < 2; kk++) {
        bf16x8 bv = *(const bf16x8*)(&Vt[nbh * 16 + lr][kk * 32 + lhi * 8]);
        acc_o[nbh] = __builtin_amdgcn_mfma_f32_16x16x32_bf16(ap[kk], bv, acc_o[nbh], 0, 0, 0);
      }
    }
    __syncthreads();  // all waves done with Vt before next overwrite
  }

  // epilogue: out[b][s][h*64+hd] = acc/l
  const int b = bh >> 4, h = bh & 15;
#pragma unroll
  for (int nbh = 0; nbh < 4; nbh++) {
#pragma unroll
    for (int r = 0; r < 4; r++) {
      int s = q0 + w * 16 + lhi * 4 + r;
      float vv = acc_o[nbh][r] / lsum[r];
      out[((size_t)(b * SEQ + s)) * DMODEL + h * HD + nbh * 16 + lr] = vv;
    }
  }
}

extern "C" void kernel_launch(void* const* d_in, const int* in_sizes, int n_in,
                              void* d_out, int out_size, void* d_ws, size_t ws_size,
                              hipStream_t stream) {
  const float* query = (const float*)d_in[0];
  const float* key_  = (const float*)d_in[1];
  const float* value = (const float*)d_in[2];
  const float* Wq = (const float*)d_in[3];
  const float* bq = (const float*)d_in[4];
  const float* Wk = (const float*)d_in[5];
  const float* bk = (const float*)d_in[6];
  const float* Wv = (const float*)d_in[7];
  const float* bv = (const float*)d_in[8];

  ushort* Wb = (ushort*)d_ws;                       // 3 * 1M bf16
  ushort* qkv = Wb + 3u * 1048576u;                 // 3 * 8.39M bf16

  convert_w<<<dim3(1024, 3), 256, 0, stream>>>(Wq, Wk, Wv, Wb);
  qkv_gemm<<<dim3(64, 8, 3), 256, 0, stream>>>(query, key_, value, Wb, bq, bk, bv, qkv);
  attn_kernel<<<dim3(BHTOT * (SEQ / 64)), 256, 0, stream>>>(qkv, (float*)d_out);
}